// Round 13
// baseline (476.329 us; speedup 1.0000x reference)
//
#include <hip/hip_runtime.h>

// Chamfer distance via bf16 MFMA with split-bf16 (hi+lo) distance packing.
// B=4, N=M=8192, f32 in/out. out = [dist1 (B*N) | dist2 (B*M)].
//
// d[i][j] = |q_i|^2 + |r_j|^2 - 2 q_i.r_j computed entirely inside
// v_mfma_f32_32x32x16_bf16 via K=16 slot packing (see chamfer_prep).
//
// R11 = DIRECTION DEDUP: each D-block is computed ONCE; dist1 comes from the
// in-register row-min path (proven R10), dist2 from a per-tile col-min
// (min-tree over the 32 accs + __shfl_xor(32) + LDS atomicMin into
// colmin[1024], flushed once per block). Halves MFMAs / A-loads / staging /
// grid vs R10. All proven pieces kept: one-barrier 32KB B staging with
// pre-baked swizzle, nested-fminf folds (NO inline-asm min on MFMA outputs
// — the R3/R4 hazard bug), verified D layout, separate out-init.

typedef __bf16 bf16_t;
typedef __bf16 bf16x8 __attribute__((ext_vector_type(8)));
typedef float  f32x16 __attribute__((ext_vector_type(16)));

#define NPTS    8192
#define NB      4
#define NSETPTS (NB * NPTS)          // 32768 points per set
#define TPB     256
#define WAVES   4
#define QPW     2                    // q-tiles (of 32 rows) per wave
#define QC      (WAVES * QPW * 32)   // 256 query rows per block
#define QPANELS (NPTS / QC)          // 32
#define SEGR    8                    // ref-dim split
#define RC      (NPTS / SEGR)        // 1024 refs per block sweep
#define RT      (RC / 32)            // 32 r-tiles per sweep
#define NSLOT   (RC * 2)             // 16B slots in the B segment (2048)

__global__ void chamfer_init_out(unsigned int* __restrict__ out, int n) {
    int i = blockIdx.x * blockDim.x + threadIdx.x;
    if (i < n) out[i] = 0x7F800000u;  // +inf bits
}

__device__ __forceinline__ void gload16(const bf16_t* g, bf16_t* l) {
    __builtin_amdgcn_global_load_lds(
        (const __attribute__((address_space(1))) void*)g,
        (__attribute__((address_space(3))) void*)l, 16, 0, 0);
}

__device__ __forceinline__ void split2(float v, bf16_t& h, bf16_t& l) {
    h = (bf16_t)v;
    l = (bf16_t)(v - (float)h);
}

// A-pack for xyz1 (linear), B-pack for xyz2 (tile-local slot swizzle
// s -> s ^ (p&7), proven R9/R10). stored[j] = logical[perm[j]],
// perm = {0,1,2,3, 8,9,10,11, 4,5,6,7, 12,13,14,15} (fragment halves).
// Slots: k0-2 (-2q)_hi*r_hi | k3-5 (-2q)_lo*r_hi | k6-8 (-2q)_hi*r_lo |
//        k9-10 |q|^2 hi/lo * 1 | k11-12 1 * |r|^2 hi/lo | k13-15 zero.
__global__ void chamfer_prep(const float* __restrict__ xyz1,
                             const float* __restrict__ xyz2,
                             bf16_t* __restrict__ a16,
                             bf16_t* __restrict__ b16) {
    int i = blockIdx.x * blockDim.x + threadIdx.x;   // 0..NSETPTS-1
    const int perm[16] = {0,1,2,3, 8,9,10,11, 4,5,6,7, 12,13,14,15};

    // ---- A side (query = xyz1) ----
    {
        float x = xyz1[3 * i], y = xyz1[3 * i + 1], z = xyz1[3 * i + 2];
        float sq = x * x + y * y + z * z;
        bf16_t m2xh, m2xl, m2yh, m2yl, m2zh, m2zl, sqh, sql;
        split2(-2.f * x, m2xh, m2xl);
        split2(-2.f * y, m2yh, m2yl);
        split2(-2.f * z, m2zh, m2zl);
        split2(sq, sqh, sql);
        bf16_t one = (bf16_t)1.0f, zero = (bf16_t)0.0f;
        bf16_t A[16] = { m2xh, m2yh, m2zh,  m2xl, m2yl, m2zl,
                         m2xh, m2yh, m2zh,  sqh, sql, one, one, zero, zero, zero };
        bf16_t* ao = a16 + (size_t)i * 16;
#pragma unroll
        for (int j = 0; j < 16; ++j) ao[j] = A[perm[j]];
    }

    // ---- B side (reference = xyz2), swizzled ----
    {
        float x = xyz2[3 * i], y = xyz2[3 * i + 1], z = xyz2[3 * i + 2];
        float sq = x * x + y * y + z * z;
        bf16_t xh, xl, yh, yl, zh, zl, sqh, sql;
        split2(x, xh, xl);
        split2(y, yh, yl);
        split2(z, zh, zl);
        split2(sq, sqh, sql);
        bf16_t one = (bf16_t)1.0f, zero = (bf16_t)0.0f;
        bf16_t Bv[16] = { xh, yh, zh,  xh, yh, zh,  xl, yl, zl,
                          one, one, sqh, sql, zero, zero, zero };
        int p = i & 31;
        size_t tb = (size_t)(i & ~31) * 16;          // tile base (bf16 elems)
        int s0 = (2 * p)     ^ (p & 7);
        int s1 = (2 * p + 1) ^ (p & 7);
        bf16_t* bo0 = b16 + tb + (size_t)s0 * 8;
        bf16_t* bo1 = b16 + tb + (size_t)s1 * 8;
#pragma unroll
        for (int j = 0; j < 8; ++j) bo0[j] = Bv[perm[j]];
#pragma unroll
        for (int j = 0; j < 8; ++j) bo1[j] = Bv[perm[j + 8]];
    }
}

__global__ __launch_bounds__(TPB, 4) void chamfer_main(
    const bf16_t* __restrict__ a16,
    const bf16_t* __restrict__ b16,
    unsigned int* __restrict__ out)
{
    // B segment (32KB) during compute; row-reduce scratch (16.9KB) aliases it.
    __shared__ __align__(16) unsigned char smem[NSLOT * 16];
    __shared__ unsigned int colmin[RC];               // 4KB, separate
    bf16_t* sbuf = (bf16_t*)smem;
    float (*red)[32][33] = (float (*)[32][33])smem;   // [WAVES][32][33]

    int bid = blockIdx.x;
    int s   = bid & (SEGR - 1);    bid >>= 3;   // reference segment
    int qp  = bid & (QPANELS - 1); bid >>= 5;   // q-panel
    int b   = bid;                              // batch

    int wave = threadIdx.x >> 6;
    int lane = threadIdx.x & 63;
    int col  = lane & 31;
    int h    = lane >> 5;

    const bf16_t* ap = a16 + (size_t)b * NPTS * 16;
    const bf16_t* gB = b16 + (size_t)(b * NPTS + s * RC) * 16;

    // Stage the whole 32KB B segment: 8 rounds x 256 threads x 16B.
#pragma unroll
    for (int c = 0; c < 8; ++c) {
        int slot = c * 256 + threadIdx.x;
        gload16(gB + (size_t)slot * 8, sbuf + (size_t)slot * 8);
    }

    // colmin init (LDS writes; drained by the same barrier).
#pragma unroll
    for (int k = 0; k < RC / TPB; ++k)
        colmin[k * TPB + threadIdx.x] = 0x7F800000u;

    // A fragments (direct global, once per sweep).
    int qbase = qp * QC + wave * (QPW * 32);
    bf16x8 af0 = *((const bf16x8*)(ap + (size_t)(qbase +  0 + col) * 16) + h);
    bf16x8 af1 = *((const bf16x8*)(ap + (size_t)(qbase + 32 + col) * 16) + h);

    f32x16 rm0, rm1, zacc;
#pragma unroll
    for (int g = 0; g < 16; ++g) {
        rm0[g] = INFINITY; rm1[g] = INFINITY; zacc[g] = 0.f;
    }

    __syncthreads();   // ONE barrier: staged B + colmin init visible

    int swz = ((2 * col + h) ^ (col & 7)) * 8;
    const bf16_t* sl = sbuf + swz;

    bf16x8 c0 = *(const bf16x8*)(sl + 0 * 512);
    bf16x8 c1 = *(const bf16x8*)(sl + 1 * 512);
#pragma unroll
    for (int t = 0; t < RT; t += 2) {
        bf16x8 p0, p1;
        if (t + 2 < RT) {
            p0 = *(const bf16x8*)(sl + (t + 2) * 512);
            p1 = *(const bf16x8*)(sl + (t + 3) * 512);
        }

        f32x16 x0 = __builtin_amdgcn_mfma_f32_32x32x16_bf16(af0, c0, zacc, 0, 0, 0);
        f32x16 x1 = __builtin_amdgcn_mfma_f32_32x32x16_bf16(af0, c1, zacc, 0, 0, 0);
#pragma unroll
        for (int g = 0; g < 16; ++g) rm0[g] = fminf(fminf(x0[g], x1[g]), rm0[g]);

        f32x16 x2 = __builtin_amdgcn_mfma_f32_32x32x16_bf16(af1, c0, zacc, 0, 0, 0);
        f32x16 x3 = __builtin_amdgcn_mfma_f32_32x32x16_bf16(af1, c1, zacc, 0, 0, 0);
#pragma unroll
        for (int g = 0; g < 16; ++g) rm1[g] = fminf(fminf(x2[g], x3[g]), rm1[g]);

        // Col-mins (dist2): manual min-trees over both q-tiles' accs.
        {
            float u0[8], u1[8];
#pragma unroll
            for (int k = 0; k < 8; ++k) {
                u0[k] = fminf(fminf(x0[2*k], x2[2*k]), fminf(x0[2*k+1], x2[2*k+1]));
                u1[k] = fminf(fminf(x1[2*k], x3[2*k]), fminf(x1[2*k+1], x3[2*k+1]));
            }
#pragma unroll
            for (int k = 0; k < 4; ++k) {
                u0[k] = fminf(u0[k], u0[k + 4]);
                u1[k] = fminf(u1[k], u1[k + 4]);
            }
            float m0 = fminf(fminf(u0[0], u0[1]), fminf(u0[2], u0[3]));
            float m1 = fminf(fminf(u1[0], u1[1]), fminf(u1[2], u1[3]));
            m0 = fminf(m0, __shfl_xor(m0, 32));   // other h-half (rows +/-4)
            m1 = fminf(m1, __shfl_xor(m1, 32));
            m0 = fmaxf(m0, 0.f);                   // clamp-early == clamp-late
            m1 = fmaxf(m1, 0.f);
            if (h == 0) {
                atomicMin(&colmin[t * 32 + col],       __float_as_uint(m0));
                atomicMin(&colmin[(t + 1) * 32 + col], __float_as_uint(m1));
            }
        }

        if (t + 2 < RT) { c0 = p0; c1 = p1; }
    }

    __syncthreads();   // B consumed (red may alias sbuf); colmin complete

    // Flush col-mins (dist2 partials): 4 entries/thread, one atomic each.
    {
        int out2base = NSETPTS + b * NPTS + s * RC;
#pragma unroll
        for (int k = 0; k < RC / TPB; ++k) {
            int j = k * TPB + threadIdx.x;
            atomicMin(&out[out2base + j], colmin[j]);
        }
    }

    int outbase = b * NPTS + qp * QC;

    // Row-reduce passes (dist1), proven LDS-red pattern.
    // D row = (g&3) + 8*(g>>2) + 4*h (verified layout).
#define RED_PASS(QT, RM)                                                      \
    {                                                                         \
        _Pragma("unroll")                                                     \
        for (int g = 0; g < 16; ++g) {                                        \
            int row = (g & 3) + 8 * (g >> 2) + 4 * h;                         \
            red[wave][row][col] = RM[g];                                      \
        }                                                                     \
        __syncthreads();                                                      \
        if (threadIdx.x < 128) {                                              \
            int w = threadIdx.x >> 5, r = threadIdx.x & 31;                   \
            const float* rp = &red[w][r][0];                                  \
            float v0 = rp[0], v1 = rp[1], v2 = rp[2], v3 = rp[3];             \
            _Pragma("unroll")                                                 \
            for (int cc = 4; cc < 32; cc += 4) {                              \
                v0 = fminf(v0, rp[cc + 0]);                                   \
                v1 = fminf(v1, rp[cc + 1]);                                   \
                v2 = fminf(v2, rp[cc + 2]);                                   \
                v3 = fminf(v3, rp[cc + 3]);                                   \
            }                                                                 \
            float v = fmaxf(fminf(fminf(v0, v1), fminf(v2, v3)), 0.f);        \
            atomicMin(&out[outbase + w * (QPW * 32) + (QT) * 32 + r],         \
                      __float_as_uint(v));                                    \
        }                                                                     \
        __syncthreads();                                                      \
    }

    RED_PASS(0, rm0)
    RED_PASS(1, rm1)
#undef RED_PASS
}

extern "C" void kernel_launch(void* const* d_in, const int* in_sizes, int n_in,
                              void* d_out, int out_size, void* d_ws, size_t ws_size,
                              hipStream_t stream) {
    const float* xyz1 = (const float*)d_in[0];
    const float* xyz2 = (const float*)d_in[1];
    unsigned int* out = (unsigned int*)d_out;

    bf16_t* a16 = (bf16_t*)d_ws;                          // 1 MB
    bf16_t* b16 = a16 + (size_t)NSETPTS * 16;             // +1 MB

    hipLaunchKernelGGL(chamfer_init_out,
                       dim3((out_size + TPB - 1) / TPB), dim3(TPB), 0, stream,
                       out, out_size);

    hipLaunchKernelGGL(chamfer_prep,
                       dim3(NSETPTS / TPB), dim3(TPB), 0, stream,
                       xyz1, xyz2, a16, b16);

    // 4 batches x 32 q-panels x 8 ref-segments = 1024 blocks
    hipLaunchKernelGGL(chamfer_main,
                       dim3(NB * QPANELS * SEGR), dim3(TPB), 0, stream,
                       a16, b16, out);
}

// Round 14
// 79.721 us; speedup vs baseline: 5.9749x; 5.9749x over previous
//
#include <hip/hip_runtime.h>

// Chamfer distance via bf16 MFMA with split-bf16 (hi+lo) distance packing.
// B=4, N=M=8192, f32 in/out. out = [dist1 (B*N) | dist2 (B*M)].
//
// d[i][j] = |q_i|^2 + |r_j|^2 - 2 q_i.r_j computed entirely inside
// v_mfma_f32_32x32x16_bf16 via K=16 slot packing (see chamfer_prep).
//
// R14 = R13's direction dedup with the SPILL fixed (R13: 1.5GB scratch
// traffic, 447us): no full unroll of the RT loop, incremental col-min
// (each acc tuple collapsed to a scalar immediately -> max 2 tuples live),
// no register prefetch ring. Max ~110 VGPR < 128 cap.

typedef __bf16 bf16_t;
typedef __bf16 bf16x8 __attribute__((ext_vector_type(8)));
typedef float  f32x16 __attribute__((ext_vector_type(16)));

#define NPTS    8192
#define NB      4
#define NSETPTS (NB * NPTS)          // 32768 points per set
#define TPB     256
#define WAVES   4
#define QPW     2                    // q-tiles (of 32 rows) per wave
#define QC      (WAVES * QPW * 32)   // 256 query rows per block
#define QPANELS (NPTS / QC)          // 32
#define SEGR    8                    // ref-dim split
#define RC      (NPTS / SEGR)        // 1024 refs per block sweep
#define RT      (RC / 32)            // 32 r-tiles per sweep
#define NSLOT   (RC * 2)             // 16B slots in the B segment (2048)

__global__ void chamfer_init_out(unsigned int* __restrict__ out, int n) {
    int i = blockIdx.x * blockDim.x + threadIdx.x;
    if (i < n) out[i] = 0x7F800000u;  // +inf bits
}

__device__ __forceinline__ void gload16(const bf16_t* g, bf16_t* l) {
    __builtin_amdgcn_global_load_lds(
        (const __attribute__((address_space(1))) void*)g,
        (__attribute__((address_space(3))) void*)l, 16, 0, 0);
}

__device__ __forceinline__ void split2(float v, bf16_t& h, bf16_t& l) {
    h = (bf16_t)v;
    l = (bf16_t)(v - (float)h);
}

// 15-op min tree collapsing one acc tuple to a scalar (frees the tuple).
__device__ __forceinline__ float tree16(const f32x16& x) {
    float a0 = fminf(x[0],  x[1]);
    float a1 = fminf(x[2],  x[3]);
    float a2 = fminf(x[4],  x[5]);
    float a3 = fminf(x[6],  x[7]);
    float a4 = fminf(x[8],  x[9]);
    float a5 = fminf(x[10], x[11]);
    float a6 = fminf(x[12], x[13]);
    float a7 = fminf(x[14], x[15]);
    a0 = fminf(a0, a1); a2 = fminf(a2, a3);
    a4 = fminf(a4, a5); a6 = fminf(a6, a7);
    return fminf(fminf(a0, a2), fminf(a4, a6));
}

// A-pack for xyz1 (linear), B-pack for xyz2 (tile-local slot swizzle
// s -> s ^ (p&7), proven R9/R10). stored[j] = logical[perm[j]],
// perm = {0,1,2,3, 8,9,10,11, 4,5,6,7, 12,13,14,15} (fragment halves).
// Slots: k0-2 (-2q)_hi*r_hi | k3-5 (-2q)_lo*r_hi | k6-8 (-2q)_hi*r_lo |
//        k9-10 |q|^2 hi/lo * 1 | k11-12 1 * |r|^2 hi/lo | k13-15 zero.
__global__ void chamfer_prep(const float* __restrict__ xyz1,
                             const float* __restrict__ xyz2,
                             bf16_t* __restrict__ a16,
                             bf16_t* __restrict__ b16) {
    int i = blockIdx.x * blockDim.x + threadIdx.x;   // 0..NSETPTS-1
    const int perm[16] = {0,1,2,3, 8,9,10,11, 4,5,6,7, 12,13,14,15};

    // ---- A side (query = xyz1) ----
    {
        float x = xyz1[3 * i], y = xyz1[3 * i + 1], z = xyz1[3 * i + 2];
        float sq = x * x + y * y + z * z;
        bf16_t m2xh, m2xl, m2yh, m2yl, m2zh, m2zl, sqh, sql;
        split2(-2.f * x, m2xh, m2xl);
        split2(-2.f * y, m2yh, m2yl);
        split2(-2.f * z, m2zh, m2zl);
        split2(sq, sqh, sql);
        bf16_t one = (bf16_t)1.0f, zero = (bf16_t)0.0f;
        bf16_t A[16] = { m2xh, m2yh, m2zh,  m2xl, m2yl, m2zl,
                         m2xh, m2yh, m2zh,  sqh, sql, one, one, zero, zero, zero };
        bf16_t* ao = a16 + (size_t)i * 16;
#pragma unroll
        for (int j = 0; j < 16; ++j) ao[j] = A[perm[j]];
    }

    // ---- B side (reference = xyz2), swizzled ----
    {
        float x = xyz2[3 * i], y = xyz2[3 * i + 1], z = xyz2[3 * i + 2];
        float sq = x * x + y * y + z * z;
        bf16_t xh, xl, yh, yl, zh, zl, sqh, sql;
        split2(x, xh, xl);
        split2(y, yh, yl);
        split2(z, zh, zl);
        split2(sq, sqh, sql);
        bf16_t one = (bf16_t)1.0f, zero = (bf16_t)0.0f;
        bf16_t Bv[16] = { xh, yh, zh,  xh, yh, zh,  xl, yl, zl,
                          one, one, sqh, sql, zero, zero, zero };
        int p = i & 31;
        size_t tb = (size_t)(i & ~31) * 16;          // tile base (bf16 elems)
        int s0 = (2 * p)     ^ (p & 7);
        int s1 = (2 * p + 1) ^ (p & 7);
        bf16_t* bo0 = b16 + tb + (size_t)s0 * 8;
        bf16_t* bo1 = b16 + tb + (size_t)s1 * 8;
#pragma unroll
        for (int j = 0; j < 8; ++j) bo0[j] = Bv[perm[j]];
#pragma unroll
        for (int j = 0; j < 8; ++j) bo1[j] = Bv[perm[j + 8]];
    }
}

__global__ __launch_bounds__(TPB, 4) void chamfer_main(
    const bf16_t* __restrict__ a16,
    const bf16_t* __restrict__ b16,
    unsigned int* __restrict__ out)
{
    // B segment (32KB) during compute; row-reduce scratch (16.9KB) aliases it.
    __shared__ __align__(16) unsigned char smem[NSLOT * 16];
    __shared__ unsigned int colmin[RC];               // 4KB, separate
    bf16_t* sbuf = (bf16_t*)smem;
    float (*red)[32][33] = (float (*)[32][33])smem;   // [WAVES][32][33]

    int bid = blockIdx.x;
    int s   = bid & (SEGR - 1);    bid >>= 3;   // reference segment
    int qp  = bid & (QPANELS - 1); bid >>= 5;   // q-panel
    int b   = bid;                              // batch

    int wave = threadIdx.x >> 6;
    int lane = threadIdx.x & 63;
    int col  = lane & 31;
    int h    = lane >> 5;

    const bf16_t* ap = a16 + (size_t)b * NPTS * 16;
    const bf16_t* gB = b16 + (size_t)(b * NPTS + s * RC) * 16;

    // Stage the whole 32KB B segment: 8 rounds x 256 threads x 16B.
#pragma unroll
    for (int c = 0; c < 8; ++c) {
        int slot = c * 256 + threadIdx.x;
        gload16(gB + (size_t)slot * 8, sbuf + (size_t)slot * 8);
    }

    // colmin init (LDS writes; drained by the same barrier).
#pragma unroll
    for (int k = 0; k < RC / TPB; ++k)
        colmin[k * TPB + threadIdx.x] = 0x7F800000u;

    // A fragments (direct global, once per sweep).
    int qbase = qp * QC + wave * (QPW * 32);
    bf16x8 af0 = *((const bf16x8*)(ap + (size_t)(qbase +  0 + col) * 16) + h);
    bf16x8 af1 = *((const bf16x8*)(ap + (size_t)(qbase + 32 + col) * 16) + h);

    f32x16 rm0, rm1, zacc;
#pragma unroll
    for (int g = 0; g < 16; ++g) {
        rm0[g] = INFINITY; rm1[g] = INFINITY; zacc[g] = 0.f;
    }

    __syncthreads();   // ONE barrier: staged B + colmin init visible

    int swz = ((2 * col + h) ^ (col & 7)) * 8;
    const bf16_t* sl = sbuf + swz;

#pragma unroll 1   // NO full unroll (R13's spill cause)
    for (int t = 0; t < RT; t += 2) {
        bf16x8 c0 = *(const bf16x8*)(sl + (size_t)(t + 0) * 512);
        bf16x8 c1 = *(const bf16x8*)(sl + (size_t)(t + 1) * 512);

        // q-tile 0: row fold + per-tuple col collapse (tuples die here).
        f32x16 x0 = __builtin_amdgcn_mfma_f32_32x32x16_bf16(af0, c0, zacc, 0, 0, 0);
        f32x16 x1 = __builtin_amdgcn_mfma_f32_32x32x16_bf16(af0, c1, zacc, 0, 0, 0);
#pragma unroll
        for (int g = 0; g < 16; ++g) rm0[g] = fminf(fminf(x0[g], x1[g]), rm0[g]);
        float s0 = tree16(x0);
        float s1 = tree16(x1);

        // q-tile 1.
        f32x16 x2 = __builtin_amdgcn_mfma_f32_32x32x16_bf16(af1, c0, zacc, 0, 0, 0);
        f32x16 x3 = __builtin_amdgcn_mfma_f32_32x32x16_bf16(af1, c1, zacc, 0, 0, 0);
#pragma unroll
        for (int g = 0; g < 16; ++g) rm1[g] = fminf(fminf(x2[g], x3[g]), rm1[g]);
        float s2 = tree16(x2);
        float s3 = tree16(x3);

        // Col-mins (dist2) for tiles t, t+1.
        float m0 = fminf(s0, s2);
        float m1 = fminf(s1, s3);
        m0 = fminf(m0, __shfl_xor(m0, 32));   // other h-half (rows +/-4)
        m1 = fminf(m1, __shfl_xor(m1, 32));
        m0 = fmaxf(m0, 0.f);                   // clamp-early == clamp-late
        m1 = fmaxf(m1, 0.f);
        if (h == 0) {
            atomicMin(&colmin[t * 32 + col],       __float_as_uint(m0));
            atomicMin(&colmin[(t + 1) * 32 + col], __float_as_uint(m1));
        }
    }

    __syncthreads();   // B consumed (red may alias sbuf); colmin complete

    // Flush col-mins (dist2 partials): 4 entries/thread, one atomic each.
    {
        int out2base = NSETPTS + b * NPTS + s * RC;
#pragma unroll
        for (int k = 0; k < RC / TPB; ++k) {
            int j = k * TPB + threadIdx.x;
            atomicMin(&out[out2base + j], colmin[j]);
        }
    }

    int outbase = b * NPTS + qp * QC;

    // Row-reduce passes (dist1), proven LDS-red pattern.
    // D row = (g&3) + 8*(g>>2) + 4*h (verified layout).
#define RED_PASS(QT, RM)                                                      \
    {                                                                         \
        _Pragma("unroll")                                                     \
        for (int g = 0; g < 16; ++g) {                                        \
            int row = (g & 3) + 8 * (g >> 2) + 4 * h;                         \
            red[wave][row][col] = RM[g];                                      \
        }                                                                     \
        __syncthreads();                                                      \
        if (threadIdx.x < 128) {                                              \
            int w = threadIdx.x >> 5, r = threadIdx.x & 31;                   \
            const float* rp = &red[w][r][0];                                  \
            float v0 = rp[0], v1 = rp[1], v2 = rp[2], v3 = rp[3];             \
            _Pragma("unroll")                                                 \
            for (int cc = 4; cc < 32; cc += 4) {                              \
                v0 = fminf(v0, rp[cc + 0]);                                   \
                v1 = fminf(v1, rp[cc + 1]);                                   \
                v2 = fminf(v2, rp[cc + 2]);                                   \
                v3 = fminf(v3, rp[cc + 3]);                                   \
            }                                                                 \
            float v = fmaxf(fminf(fminf(v0, v1), fminf(v2, v3)), 0.f);        \
            atomicMin(&out[outbase + w * (QPW * 32) + (QT) * 32 + r],         \
                      __float_as_uint(v));                                    \
        }                                                                     \
        __syncthreads();                                                      \
    }

    RED_PASS(0, rm0)
    RED_PASS(1, rm1)
#undef RED_PASS
}

extern "C" void kernel_launch(void* const* d_in, const int* in_sizes, int n_in,
                              void* d_out, int out_size, void* d_ws, size_t ws_size,
                              hipStream_t stream) {
    const float* xyz1 = (const float*)d_in[0];
    const float* xyz2 = (const float*)d_in[1];
    unsigned int* out = (unsigned int*)d_out;

    bf16_t* a16 = (bf16_t*)d_ws;                          // 1 MB
    bf16_t* b16 = a16 + (size_t)NSETPTS * 16;             // +1 MB

    hipLaunchKernelGGL(chamfer_init_out,
                       dim3((out_size + TPB - 1) / TPB), dim3(TPB), 0, stream,
                       out, out_size);

    hipLaunchKernelGGL(chamfer_prep,
                       dim3(NSETPTS / TPB), dim3(TPB), 0, stream,
                       xyz1, xyz2, a16, b16);

    // 4 batches x 32 q-panels x 8 ref-segments = 1024 blocks
    hipLaunchKernelGGL(chamfer_main,
                       dim3(NB * QPANELS * SEGR), dim3(TPB), 0, stream,
                       a16, b16, out);
}

// Round 15
// 79.439 us; speedup vs baseline: 5.9962x; 1.0035x over previous
//
#include <hip/hip_runtime.h>

// Chamfer distance via bf16 MFMA with split-bf16 (hi+lo) distance packing.
// B=4, N=M=8192, f32 in/out. out = [dist1 (B*N) | dist2 (B*M)].
//
// d[i][j] = |q_i|^2 + |r_j|^2 - 2 q_i.r_j computed entirely inside
// v_mfma_f32_32x32x16_bf16 via K=16 slot packing (see chamfer_prep).
//
// R15 = R14's dedup structure tuned for OCCUPANCY (the only lever with a
// measured win: R9->R10 2->4 waves/SIMD = -7us on main):
//   - QPW=1 (VGPR peak ~88; plain __launch_bounds__(256) — the (256,4)
//     variant empirically pinned VGPR=64 and triggered R13's spill)
//   - SEGR=16, RC=512: ~19KB LDS/block -> ~5 blocks/CU residency
//   - min3-shaped tree16 (8 inst vs 15)
// Proven pieces kept verbatim: K=16 packing, pre-baked B swizzle,
// one-barrier whole-segment staging, nested-fminf folds (NO inline-asm
// min on MFMA outputs — the R3/R4 hazard), verified D layout, dedup
// row+col extraction, separate out-init.

typedef __bf16 bf16_t;
typedef __bf16 bf16x8 __attribute__((ext_vector_type(8)));
typedef float  f32x16 __attribute__((ext_vector_type(16)));

#define NPTS    8192
#define NB      4
#define NSETPTS (NB * NPTS)          // 32768 points per set
#define TPB     256
#define WAVES   4
#define QC      (WAVES * 32)         // 128 query rows per block (QPW=1)
#define QPANELS (NPTS / QC)          // 64
#define SEGR    16                   // ref-dim split
#define RC      (NPTS / SEGR)        // 512 refs per block sweep
#define RT      (RC / 32)            // 16 r-tiles per sweep
#define NSLOT   (RC * 2)             // 16B slots in the B segment (1024)

__global__ void chamfer_init_out(unsigned int* __restrict__ out, int n) {
    int i = blockIdx.x * blockDim.x + threadIdx.x;
    if (i < n) out[i] = 0x7F800000u;  // +inf bits
}

__device__ __forceinline__ void gload16(const bf16_t* g, bf16_t* l) {
    __builtin_amdgcn_global_load_lds(
        (const __attribute__((address_space(1))) void*)g,
        (__attribute__((address_space(3))) void*)l, 16, 0, 0);
}

__device__ __forceinline__ void split2(float v, bf16_t& h, bf16_t& l) {
    h = (bf16_t)v;
    l = (bf16_t)(v - (float)h);
}

// Col collapse of one acc tuple, shaped for v_min3_f32 fusion (8 inst).
__device__ __forceinline__ float tree16(const f32x16& x) {
    float a = fminf(fminf(x[0],  x[1]),  x[2]);
    float b = fminf(fminf(x[3],  x[4]),  x[5]);
    float c = fminf(fminf(x[6],  x[7]),  x[8]);
    float d = fminf(fminf(x[9],  x[10]), x[11]);
    float e = fminf(fminf(x[12], x[13]), x[14]);
    a = fminf(fminf(a, b), x[15]);
    c = fminf(fminf(c, d), e);
    return fminf(a, c);
}

// A-pack for xyz1 (linear), B-pack for xyz2 (tile-local slot swizzle
// s -> s ^ (p&7), proven R9/R10/R14). stored[j] = logical[perm[j]],
// perm = {0,1,2,3, 8,9,10,11, 4,5,6,7, 12,13,14,15} (fragment halves).
// Slots: k0-2 (-2q)_hi*r_hi | k3-5 (-2q)_lo*r_hi | k6-8 (-2q)_hi*r_lo |
//        k9-10 |q|^2 hi/lo * 1 | k11-12 1 * |r|^2 hi/lo | k13-15 zero.
__global__ void chamfer_prep(const float* __restrict__ xyz1,
                             const float* __restrict__ xyz2,
                             bf16_t* __restrict__ a16,
                             bf16_t* __restrict__ b16) {
    int i = blockIdx.x * blockDim.x + threadIdx.x;   // 0..NSETPTS-1
    const int perm[16] = {0,1,2,3, 8,9,10,11, 4,5,6,7, 12,13,14,15};

    // ---- A side (query = xyz1) ----
    {
        float x = xyz1[3 * i], y = xyz1[3 * i + 1], z = xyz1[3 * i + 2];
        float sq = x * x + y * y + z * z;
        bf16_t m2xh, m2xl, m2yh, m2yl, m2zh, m2zl, sqh, sql;
        split2(-2.f * x, m2xh, m2xl);
        split2(-2.f * y, m2yh, m2yl);
        split2(-2.f * z, m2zh, m2zl);
        split2(sq, sqh, sql);
        bf16_t one = (bf16_t)1.0f, zero = (bf16_t)0.0f;
        bf16_t A[16] = { m2xh, m2yh, m2zh,  m2xl, m2yl, m2zl,
                         m2xh, m2yh, m2zh,  sqh, sql, one, one, zero, zero, zero };
        bf16_t* ao = a16 + (size_t)i * 16;
#pragma unroll
        for (int j = 0; j < 16; ++j) ao[j] = A[perm[j]];
    }

    // ---- B side (reference = xyz2), swizzled ----
    {
        float x = xyz2[3 * i], y = xyz2[3 * i + 1], z = xyz2[3 * i + 2];
        float sq = x * x + y * y + z * z;
        bf16_t xh, xl, yh, yl, zh, zl, sqh, sql;
        split2(x, xh, xl);
        split2(y, yh, yl);
        split2(z, zh, zl);
        split2(sq, sqh, sql);
        bf16_t one = (bf16_t)1.0f, zero = (bf16_t)0.0f;
        bf16_t Bv[16] = { xh, yh, zh,  xh, yh, zh,  xl, yl, zl,
                          one, one, sqh, sql, zero, zero, zero };
        int p = i & 31;
        size_t tb = (size_t)(i & ~31) * 16;          // tile base (bf16 elems)
        int s0 = (2 * p)     ^ (p & 7);
        int s1 = (2 * p + 1) ^ (p & 7);
        bf16_t* bo0 = b16 + tb + (size_t)s0 * 8;
        bf16_t* bo1 = b16 + tb + (size_t)s1 * 8;
#pragma unroll
        for (int j = 0; j < 8; ++j) bo0[j] = Bv[perm[j]];
#pragma unroll
        for (int j = 0; j < 8; ++j) bo1[j] = Bv[perm[j + 8]];
    }
}

__global__ __launch_bounds__(TPB) void chamfer_main(
    const bf16_t* __restrict__ a16,
    const bf16_t* __restrict__ b16,
    unsigned int* __restrict__ out)
{
    // Union: B segment (16KB) during compute; red scratch (16.9KB) after.
    __shared__ __align__(16) unsigned char smem[WAVES * 32 * 33 * 4];
    __shared__ unsigned int colmin[RC];               // 2KB, separate
    bf16_t* sbuf = (bf16_t*)smem;
    float (*red)[32][33] = (float (*)[32][33])smem;   // [WAVES][32][33]

    int bid = blockIdx.x;
    int s   = bid & (SEGR - 1);    bid >>= 4;   // reference segment
    int qp  = bid & (QPANELS - 1); bid >>= 6;   // q-panel
    int b   = bid;                              // batch

    int wave = threadIdx.x >> 6;
    int lane = threadIdx.x & 63;
    int col  = lane & 31;
    int h    = lane >> 5;

    const bf16_t* ap = a16 + (size_t)b * NPTS * 16;
    const bf16_t* gB = b16 + (size_t)(b * NPTS + s * RC) * 16;

    // Stage the whole 16KB B segment: 4 rounds x 256 threads x 16B.
#pragma unroll
    for (int c = 0; c < 4; ++c) {
        int slot = c * 256 + threadIdx.x;
        gload16(gB + (size_t)slot * 8, sbuf + (size_t)slot * 8);
    }

    // colmin init (LDS writes; drained by the same barrier).
#pragma unroll
    for (int k = 0; k < RC / TPB; ++k)
        colmin[k * TPB + threadIdx.x] = 0x7F800000u;

    // A fragment (direct global, once per sweep).
    int qbase = qp * QC + wave * 32;
    bf16x8 af = *((const bf16x8*)(ap + (size_t)(qbase + col) * 16) + h);

    f32x16 rm, zacc;
#pragma unroll
    for (int g = 0; g < 16; ++g) { rm[g] = INFINITY; zacc[g] = 0.f; }

    __syncthreads();   // ONE barrier: staged B + colmin init visible

    int swz = ((2 * col + h) ^ (col & 7)) * 8;
    const bf16_t* sl = sbuf + swz;

#pragma unroll 1   // no full unroll (R13's spill cause)
    for (int t = 0; t < RT; t += 2) {
        bf16x8 c0 = *(const bf16x8*)(sl + (size_t)(t + 0) * 512);
        bf16x8 c1 = *(const bf16x8*)(sl + (size_t)(t + 1) * 512);

        f32x16 x0 = __builtin_amdgcn_mfma_f32_32x32x16_bf16(af, c0, zacc, 0, 0, 0);
        f32x16 x1 = __builtin_amdgcn_mfma_f32_32x32x16_bf16(af, c1, zacc, 0, 0, 0);

        // Row fold (dist1): 16 x min3.
#pragma unroll
        for (int g = 0; g < 16; ++g) rm[g] = fminf(fminf(x0[g], x1[g]), rm[g]);

        // Col collapse (dist2): tuples die here (register liveness bounded).
        float s0 = tree16(x0);
        float s1 = tree16(x1);
        float m0 = fminf(s0, __shfl_xor(s0, 32));   // other h-half (rows +/-4)
        float m1 = fminf(s1, __shfl_xor(s1, 32));
        m0 = fmaxf(m0, 0.f);                        // clamp-early == clamp-late
        m1 = fmaxf(m1, 0.f);
        if (h == 0) {
            atomicMin(&colmin[t * 32 + col],       __float_as_uint(m0));
            atomicMin(&colmin[(t + 1) * 32 + col], __float_as_uint(m1));
        }
    }

    __syncthreads();   // B consumed (red may alias sbuf); colmin complete

    // Flush col-mins (dist2 partials): 2 entries/thread, one atomic each.
    {
        int out2base = NSETPTS + b * NPTS + s * RC;
#pragma unroll
        for (int k = 0; k < RC / TPB; ++k) {
            int j = k * TPB + threadIdx.x;
            atomicMin(&out[out2base + j], colmin[j]);
        }
    }

    // Row-reduce (dist1), proven LDS-red pattern.
    // D row = (g&3) + 8*(g>>2) + 4*h (verified layout).
#pragma unroll
    for (int g = 0; g < 16; ++g) {
        int row = (g & 3) + 8 * (g >> 2) + 4 * h;
        red[wave][row][col] = rm[g];
    }
    __syncthreads();

    if (threadIdx.x < QC) {
        int w = threadIdx.x >> 5, r = threadIdx.x & 31;
        const float* rp = &red[w][r][0];
        float v0 = rp[0], v1 = rp[1], v2 = rp[2], v3 = rp[3];
#pragma unroll
        for (int cc = 4; cc < 32; cc += 4) {
            v0 = fminf(v0, rp[cc + 0]);
            v1 = fminf(v1, rp[cc + 1]);
            v2 = fminf(v2, rp[cc + 2]);
            v3 = fminf(v3, rp[cc + 3]);
        }
        float v = fmaxf(fminf(fminf(v0, v1), fminf(v2, v3)), 0.f);
        atomicMin(&out[b * NPTS + qp * QC + threadIdx.x], __float_as_uint(v));
    }
}

extern "C" void kernel_launch(void* const* d_in, const int* in_sizes, int n_in,
                              void* d_out, int out_size, void* d_ws, size_t ws_size,
                              hipStream_t stream) {
    const float* xyz1 = (const float*)d_in[0];
    const float* xyz2 = (const float*)d_in[1];
    unsigned int* out = (unsigned int*)d_out;

    bf16_t* a16 = (bf16_t*)d_ws;                          // 1 MB
    bf16_t* b16 = a16 + (size_t)NSETPTS * 16;             // +1 MB

    hipLaunchKernelGGL(chamfer_init_out,
                       dim3((out_size + TPB - 1) / TPB), dim3(TPB), 0, stream,
                       out, out_size);

    hipLaunchKernelGGL(chamfer_prep,
                       dim3(NSETPTS / TPB), dim3(TPB), 0, stream,
                       xyz1, xyz2, a16, b16);

    // 4 batches x 64 q-panels x 16 ref-segments = 4096 blocks
    hipLaunchKernelGGL(chamfer_main,
                       dim3(NB * QPANELS * SEGR), dim3(TPB), 0, stream,
                       a16, b16, out);
}